// Round 5
// baseline (201.070 us; speedup 1.0000x reference)
//
#include <hip/hip_runtime.h>
#include <math.h>

#define Bc 2
#define Nc 2048
#define Ec 512
#define Hc 8
#define Dc 64
#define Mc 4096   // B*N
#define NT 32     // chunks per sequence
#define Cc 64     // chunk size

typedef short bf16x8 __attribute__((ext_vector_type(8)));
typedef float f32x4 __attribute__((ext_vector_type(4)));

// global -> LDS direct DMA, 16B per lane, dest = wave-uniform base + lane*16
#define GLOAD(g, l) __builtin_amdgcn_global_load_lds(                        \
    (const __attribute__((address_space(1))) unsigned*)(const void*)(g),     \
    (__attribute__((address_space(3))) unsigned*)(void*)(l), 16, 0, 0)

#define VMCNT(n) asm volatile("s_waitcnt vmcnt(" #n ")" ::: "memory")

__device__ __forceinline__ unsigned short f2bf(float x) {
    union { float f; unsigned u; } v; v.f = x;
    unsigned r = v.u + 0x7fffu + ((v.u >> 16) & 1u);   // RNE
    return (unsigned short)(r >> 16);
}
__device__ __forceinline__ float bf2f(unsigned short b) {
    union { float f; unsigned u; } v; v.u = ((unsigned)b) << 16;
    return v.f;
}

// gamma per head: 1 - exp(linspace(log(1/32), log(1/512), 8))
__device__ __forceinline__ float get_gamma(int h) {
    const float l0 = -3.4657359028f;
    const float l1 = -6.2383246250f;
    return 1.0f - expf(l0 + (l1 - l0) * ((float)h / 7.0f));
}

// ---------------------------------------------------------------------------
// split fp32 arrays into bf16 hi/lo pairs + xpos tables (transposed [32][2048]),
// one launch. IS tables have 1/sqrt(D)=0.125 folded in (K path).
struct SplitArgs {
    const float* src[8];
    unsigned short* hi[8];
    unsigned short* lo[8];
    int n[8];
};

__global__ __launch_bounds__(256) void prep_kernel(SplitArgs a,
                                                   float* __restrict__ sinS,
                                                   float* __restrict__ cosS,
                                                   float* __restrict__ sinIS,
                                                   float* __restrict__ cosIS) {
    int y = blockIdx.y;
    if (y == 8) {
        int idx = blockIdx.x * 256 + threadIdx.x;
        if (idx >= Nc * 32) return;
        int n = idx & 2047;
        int i = idx >> 11;                 // 0..31
        float xscale = (2.0f * (float)i + 25.6f) / 89.6f;
        float power  = ((float)n - 1024.0f) / 512.0f;
        float scale  = powf(xscale, power);
        float inv_freq = powf(10000.0f, -(float)i / 32.0f);
        float ang = (float)n * inv_freq;
        float s = sinf(ang), c = cosf(ang);
        int o = i * 2048 + n;              // transposed layout
        sinS[o]  = s * scale;
        cosS[o]  = c * scale;
        float rs = 0.125f / scale;         // fold K's 1/sqrt(D)
        sinIS[o] = s * rs;
        cosIS[o] = c * rs;
        return;
    }
    int i4 = (blockIdx.x * 256 + threadIdx.x) * 4;
    if (i4 >= a.n[y]) return;
    float4 v = *(const float4*)&a.src[y][i4];
    ushort4 h, l;
    h.x = f2bf(v.x); l.x = f2bf(v.x - bf2f(h.x));
    h.y = f2bf(v.y); l.y = f2bf(v.y - bf2f(h.y));
    h.z = f2bf(v.z); l.z = f2bf(v.z - bf2f(h.z));
    h.w = f2bf(v.w); l.w = f2bf(v.w - bf2f(h.w));
    *(ushort4*)&a.hi[y][i4] = h;
    *(ushort4*)&a.lo[y][i4] = l;
}

// ---------------------------------------------------------------------------
// bf16x3 MFMA GEMM. A (X) staged via global_load_lds double-buffer; B (W)
// loaded DIRECTLY to registers from global (L2-hot, no barrier dependency),
// double-buffered in regs. Counted vmcnt keeps prefetch loads in flight.
// x*w ~= xh*wh + xh*wl + xl*wh. Wave tile = (TM/WR) x (TN/WC).
// mode: 0=Q (xpos*scale), 1=K (xpos/scale/8 via folded tables), 2=V,
//       3=G (silu), 4=final
template<int TM, int TN, int WR, int WC>
__global__ __launch_bounds__(WR * WC * 64, 2) void mgemm_kernel(
    const unsigned short* __restrict__ Xq_h, const unsigned short* __restrict__ Xq_l,
    const unsigned short* __restrict__ Xk_h, const unsigned short* __restrict__ Xk_l,
    const unsigned short* __restrict__ Xv_h, const unsigned short* __restrict__ Xv_l,
    const unsigned short* __restrict__ Xr_h, const unsigned short* __restrict__ Xr_l,
    const unsigned short* __restrict__ Wq_h, const unsigned short* __restrict__ Wq_l,
    const unsigned short* __restrict__ Wk_h, const unsigned short* __restrict__ Wk_l,
    const unsigned short* __restrict__ Wv_h, const unsigned short* __restrict__ Wv_l,
    const unsigned short* __restrict__ Wg_h, const unsigned short* __restrict__ Wg_l,
    const unsigned short* __restrict__ Wo_h, const unsigned short* __restrict__ Wo_l,
    const float* __restrict__ bq, const float* __restrict__ bk, const float* __restrict__ bv,
    const float* __restrict__ bg, const float* __restrict__ bo,
    float* __restrict__ Qr, float* __restrict__ Kr, float* __restrict__ Vr,
    float* __restrict__ G, float* __restrict__ Out,
    const float* __restrict__ sinS, const float* __restrict__ cosS,
    const float* __restrict__ sinIS, const float* __restrict__ cosIS,
    int mode_base)
{
    constexpr int THREADS = WR * WC * 64;
    constexpr int MI  = TM / WR / 16;
    constexpr int NI  = TN / WC / 16;
    constexpr int SAh = TM * 4 / THREADS;      // A-hi GLOADs per thread per stage
    constexpr int BUF = TM * 64;               // shorts per K-step buffer (hi+lo)
    constexpr int ALo = TM * 32;               // A-lo offset (shorts)
    constexpr int XFULL = 2 * SAh + 4 * NI;    // vmcnt after full prefetch
    constexpr int XTAIL = 2 * NI;
    static_assert(XFULL == 20 || XFULL == 10, "vmcnt literal");
    static_assert(XTAIL == 8 || XTAIL == 4, "vmcnt literal");

    int mode = mode_base + blockIdx.z;
    const unsigned short *Xh, *Xl, *Wh, *Wl; const float* bias;
    switch (mode) {
        case 0:  Xh = Xq_h; Xl = Xq_l; Wh = Wq_h; Wl = Wq_l; bias = bq; break;
        case 1:  Xh = Xk_h; Xl = Xk_l; Wh = Wk_h; Wl = Wk_l; bias = bk; break;
        case 2:  Xh = Xv_h; Xl = Xv_l; Wh = Wv_h; Wl = Wv_l; bias = bv; break;
        case 3:  Xh = Xq_h; Xl = Xq_l; Wh = Wg_h; Wl = Wg_l; bias = bg; break;
        default: Xh = Xr_h; Xl = Xr_l; Wh = Wo_h; Wl = Wo_l; bias = bo; break;
    }

    __shared__ __align__(16) short lds[2 * BUF];

    int tid  = threadIdx.x;
    int lane = tid & 63;
    int w    = tid >> 6;
    int wr   = w / WC, wc = w % WC;
    int row0 = blockIdx.x * TM, col0 = blockIdx.y * TN;
    int lrow = lane & 15, lslot = lane >> 4;

    f32x4 acc[MI][NI];
    #pragma unroll
    for (int i = 0; i < MI; ++i)
        #pragma unroll
        for (int j = 0; j < NI; ++j) acc[i][j] = {0.f, 0.f, 0.f, 0.f};

    int aoff[MI];
    #pragma unroll
    for (int mi = 0; mi < MI; ++mi) {
        int r = wr * (TM / WR) + mi * 16 + lrow;
        aoff[mi] = (r * 4 + (lslot ^ ((r >> 1) & 3))) * 8;
    }
    size_t wbase[NI];
    #pragma unroll
    for (int ni = 0; ni < NI; ++ni)
        wbase[ni] = (size_t)(col0 + wc * (TN / WC) + ni * 16 + lrow) * Ec + lslot * 8;

    auto stage = [&](int buf, int k0) {
        short* l = &lds[buf * BUF];
        #pragma unroll
        for (int i = 0; i < SAh; ++i) {
            int q = i * THREADS + tid;
            int r = q >> 2;
            int sp = (q & 3) ^ ((r >> 1) & 3);       // pre-swizzled source slot
            int base = (i * THREADS + (w << 6)) * 8; // wave-uniform dest (shorts)
            size_t ga = (size_t)(row0 + r) * Ec + k0 + sp * 8;
            GLOAD(Xh + ga, &l[base]);
            GLOAD(Xl + ga, &l[ALo + base]);
        }
    };

    bf16x8 whA[NI], wlA[NI], whB[NI], wlB[NI];
    auto loadW = [&](bf16x8* dh, bf16x8* dl, int k0) {
        #pragma unroll
        for (int ni = 0; ni < NI; ++ni) {
            dh[ni] = *(const bf16x8*)(Wh + wbase[ni] + k0);
            dl[ni] = *(const bf16x8*)(Wl + wbase[ni] + k0);
        }
    };
    auto step = [&](int bufi, const bf16x8* wh, const bf16x8* wl) {
        const short* l = &lds[bufi * BUF];
        bf16x8 ah[MI], al[MI];
        #pragma unroll
        for (int mi = 0; mi < MI; ++mi) {
            ah[mi] = *(const bf16x8*)&l[aoff[mi]];
            al[mi] = *(const bf16x8*)&l[ALo + aoff[mi]];
        }
        #pragma unroll
        for (int mi = 0; mi < MI; ++mi)
            #pragma unroll
            for (int ni = 0; ni < NI; ++ni) {
                acc[mi][ni] = __builtin_amdgcn_mfma_f32_16x16x32_bf16(ah[mi], wh[ni], acc[mi][ni], 0, 0, 0);
                acc[mi][ni] = __builtin_amdgcn_mfma_f32_16x16x32_bf16(ah[mi], wl[ni], acc[mi][ni], 0, 0, 0);
                acc[mi][ni] = __builtin_amdgcn_mfma_f32_16x16x32_bf16(al[mi], wh[ni], acc[mi][ni], 0, 0, 0);
            }
        asm volatile("s_waitcnt lgkmcnt(0)" ::: "memory");
        __builtin_amdgcn_sched_barrier(0);
        __builtin_amdgcn_s_barrier();
    };

    stage(0, 0);
    loadW(whA, wlA, 0);
    for (int t = 0; t < Ec / 32; t += 2) {
        // even half: prefetch tile t+1 (always exists), consume tile t
        stage(1, (t + 1) * 32);
        loadW(whB, wlB, (t + 1) * 32);
        if constexpr (XFULL == 20) VMCNT(20); else VMCNT(10);
        __builtin_amdgcn_s_barrier();
        __builtin_amdgcn_sched_barrier(0);
        step(0, whA, wlA);
        // odd half: prefetch tile t+2 if it exists, consume tile t+1
        if (t + 2 < Ec / 32) {
            stage(0, (t + 2) * 32);
            loadW(whA, wlA, (t + 2) * 32);
            if constexpr (XFULL == 20) VMCNT(20); else VMCNT(10);
        } else {
            if constexpr (XTAIL == 8) VMCNT(8); else VMCNT(4);
        }
        __builtin_amdgcn_s_barrier();
        __builtin_amdgcn_sched_barrier(0);
        step(1, whB, wlB);
    }

    // epilogue: D[row][col]: col = lane&15, row = (lane>>4)*4 + reg
    int quad = lslot;
    if (mode <= 1) {
        const float* st = (mode == 0) ? sinS : sinIS;
        const float* ct = (mode == 0) ? cosS : cosIS;
        float* dst = (mode == 0) ? Qr : Kr;
        #pragma unroll
        for (int ni = 0; ni < NI; ++ni) {
            int c = col0 + wc * (TN / WC) + ni * 16 + lrow;
            int h = c >> 6, d = c & 63, pr = d >> 1;
            float bi = bias[c];
            #pragma unroll
            for (int mi = 0; mi < MI; ++mi) {
                int R0 = row0 + wr * (TM / WR) + mi * 16 + quad * 4;
                int bb = R0 >> 11;
                int n0 = R0 & 2047;
                float4 sv4 = *(const float4*)&st[pr * 2048 + n0];
                float4 cv4 = *(const float4*)&ct[pr * 2048 + n0];
                float svv[4] = {sv4.x, sv4.y, sv4.z, sv4.w};
                float cvv[4] = {cv4.x, cv4.y, cv4.z, cv4.w};
                #pragma unroll
                for (int reg = 0; reg < 4; ++reg) {
                    float x = acc[mi][ni][reg] + bi;
                    float p = __shfl_xor(x, 1, 64);       // partner column c^1
                    float y = (c & 1) ? fmaf(x, cvv[reg],  p * svv[reg])
                                      : fmaf(x, cvv[reg], -p * svv[reg]);
                    dst[(((size_t)(bb * Hc + h)) * Nc + n0 + reg) * Dc + d] = y;
                }
            }
        }
    } else if (mode == 2) {
        #pragma unroll
        for (int ni = 0; ni < NI; ++ni) {
            int c = col0 + wc * (TN / WC) + ni * 16 + lrow;
            int h = c >> 6, d = c & 63;
            float bi = bias[c];
            #pragma unroll
            for (int mi = 0; mi < MI; ++mi) {
                int R0 = row0 + wr * (TM / WR) + mi * 16 + quad * 4;
                int bb = R0 >> 11;
                int n0 = R0 & 2047;
                #pragma unroll
                for (int reg = 0; reg < 4; ++reg)
                    Vr[(((size_t)(bb * Hc + h)) * Nc + n0 + reg) * Dc + d] =
                        acc[mi][ni][reg] + bi;
            }
        }
    } else {
        #pragma unroll
        for (int ni = 0; ni < NI; ++ni) {
            int c = col0 + wc * (TN / WC) + ni * 16 + lrow;
            float bi = bias[c];
            #pragma unroll
            for (int mi = 0; mi < MI; ++mi) {
                int R0 = row0 + wr * (TM / WR) + mi * 16 + quad * 4;
                #pragma unroll
                for (int reg = 0; reg < 4; ++reg) {
                    float x = acc[mi][ni][reg] + bi;
                    if (mode == 3)
                        G[(size_t)(R0 + reg) * Ec + c] = x / (1.0f + expf(-x));
                    else
                        Out[(size_t)(R0 + reg) * Ec + c] = x;
                }
            }
        }
    }
}

// ---------------------------------------------------------------------------
// Phase A: per (bh, chunk) local state  L[dk][dv] = sum_s gamma^(64-s) K[s][dk] V[s][dv]
__global__ __launch_bounds__(256) void phaseA_kernel(const float* __restrict__ Kr,
                                                     const float* __restrict__ Vr,
                                                     float* __restrict__ L)
{
    int bh = blockIdx.x;
    int t  = blockIdx.y;
    float gamma = get_gamma(bh & 7);
    float lg = logf(gamma);

    __shared__ float Ks[64][68];
    __shared__ float Vs[64][68];

    int tid = threadIdx.x;
    const float* Kc = Kr + (size_t)(bh * Nc + t * Cc) * Dc;
    const float* Vc = Vr + (size_t)(bh * Nc + t * Cc) * Dc;

    #pragma unroll
    for (int i = 0; i < 4; ++i) {
        int f = tid + i * 256;
        int s = f >> 4;
        int d = (f & 15) << 2;
        float w = expf(lg * (float)(Cc - s));
        float4 kv = *(const float4*)&Kc[s * Dc + d];
        float4 ks = {kv.x * w, kv.y * w, kv.z * w, kv.w * w};
        *(float4*)&Ks[s][d] = ks;
        float4 vv = *(const float4*)&Vc[s * Dc + d];
        *(float4*)&Vs[s][d] = vv;
    }
    __syncthreads();

    int tx = tid & 15, ty = tid >> 4;
    float acc[4][4];
    #pragma unroll
    for (int i = 0; i < 4; ++i)
        #pragma unroll
        for (int j = 0; j < 4; ++j) acc[i][j] = 0.0f;

    for (int s = 0; s < 64; ++s) {
        float4 a = *(const float4*)&Ks[s][ty * 4];
        float4 b = *(const float4*)&Vs[s][tx * 4];
        float av[4] = {a.x, a.y, a.z, a.w};
        float bv[4] = {b.x, b.y, b.z, b.w};
        #pragma unroll
        for (int i = 0; i < 4; ++i)
            #pragma unroll
            for (int j = 0; j < 4; ++j)
                acc[i][j] = fmaf(av[i], bv[j], acc[i][j]);
    }

    float* Lp = L + (size_t)(bh * NT + t) * 4096;
    #pragma unroll
    for (int i = 0; i < 4; ++i) {
        float4 o = {acc[i][0], acc[i][1], acc[i][2], acc[i][3]};
        *(float4*)&Lp[(ty * 4 + i) * 64 + tx * 4] = o;
    }
}

// ---------------------------------------------------------------------------
// Phase B: S_0 = 0 ; S_{t+1} = gamma^64 * S_t + L_t  (S_t written pre-fold)
// grid (16, 4): each block owns one 1024-float quarter of the 64x64 state.
__global__ __launch_bounds__(256) void scan_kernel(const float* __restrict__ L,
                                                   float* __restrict__ Sst)
{
    int bh = blockIdx.x;
    int part = blockIdx.y;
    int tid = threadIdx.x;
    float gamma = get_gamma(bh & 7);
    float g64 = expf(logf(gamma) * 64.0f);

    float4 s = {0.0f, 0.0f, 0.0f, 0.0f};
    size_t base = (size_t)bh * NT * 4096 + part * 1024 + tid * 4;
    const float* Lp = L + base;
    float* Sp = Sst + base;
    for (int t = 0; t < NT; ++t) {
        *(float4*)&Sp[(size_t)t * 4096] = s;
        float4 l = *(const float4*)&Lp[(size_t)t * 4096];
        s.x = s.x * g64 + l.x;
        s.y = s.y * g64 + l.y;
        s.z = s.z * g64 + l.z;
        s.w = s.w * g64 + l.w;
    }
}

// ---------------------------------------------------------------------------
// Phase C: O = tril-decayed(QK^T) @ V + gamma^i * Q @ S, LayerNorm, gate,
// write retG as bf16 hi/lo in (B,N,E) layout.
__global__ __launch_bounds__(256) void phaseC_kernel(
    const float* __restrict__ Qr, const float* __restrict__ Kr, const float* __restrict__ Vr,
    const float* __restrict__ Sst, const float* __restrict__ G,
    unsigned short* __restrict__ retGh, unsigned short* __restrict__ retGl)
{
    int bh = blockIdx.x, t = blockIdx.y;
    int b = bh >> 3, h = bh & 7;
    float gamma = get_gamma(h);
    float lg = logf(gamma);

    __shared__ float QsT[64][68];
    __shared__ float KsT[64][68];
    __shared__ float Ss[64][68];

    int tid = threadIdx.x;
    const float* Qc = Qr + (size_t)(bh * Nc + t * Cc) * Dc;
    const float* Kc = Kr + (size_t)(bh * Nc + t * Cc) * Dc;
    const float* Sp = Sst + (size_t)(bh * NT + t) * 4096;

    #pragma unroll
    for (int i = 0; i < 4; ++i) {
        int f = tid + i * 256;
        int r = f >> 4;
        int d = (f & 15) << 2;
        float wq = expf(lg * (float)r);
        float4 q = *(const float4*)&Qc[r * Dc + d];
        QsT[d + 0][r] = q.x * wq; QsT[d + 1][r] = q.y * wq;
        QsT[d + 2][r] = q.z * wq; QsT[d + 3][r] = q.w * wq;
        float wk = expf(-lg * (float)r);
        float4 kk = *(const float4*)&Kc[r * Dc + d];
        KsT[d + 0][r] = kk.x * wk; KsT[d + 1][r] = kk.y * wk;
        KsT[d + 2][r] = kk.z * wk; KsT[d + 3][r] = kk.w * wk;
        float4 sv = *(const float4*)&Sp[r * 64 + d];
        *(float4*)&Ss[r][d] = sv;
    }
    __syncthreads();

    int tx = tid & 15, ty = tid >> 4;
    float accA[4][4], accO[4][4];
    #pragma unroll
    for (int i = 0; i < 4; ++i)
        #pragma unroll
        for (int j = 0; j < 4; ++j) { accA[i][j] = 0.0f; accO[i][j] = 0.0f; }

    for (int d = 0; d < 64; ++d) {
        float4 a  = *(const float4*)&QsT[d][ty * 4];
        float4 kb = *(const float4*)&KsT[d][tx * 4];
        float4 sb = *(const float4*)&Ss[d][tx * 4];
        float av[4] = {a.x, a.y, a.z, a.w};
        float kv[4] = {kb.x, kb.y, kb.z, kb.w};
        float sv[4] = {sb.x, sb.y, sb.z, sb.w};
        #pragma unroll
        for (int i = 0; i < 4; ++i)
            #pragma unroll
            for (int j = 0; j < 4; ++j) {
                accA[i][j] = fmaf(av[i], kv[j], accA[i][j]);
                accO[i][j] = fmaf(av[i], sv[j], accO[i][j]);
            }
    }
    __syncthreads();

    #pragma unroll
    for (int i = 0; i < 4; ++i) {
        int gi = ty * 4 + i;
        #pragma unroll
        for (int j = 0; j < 4; ++j) {
            int gj = tx * 4 + j;
            KsT[gj][gi] = (gj <= gi) ? accA[i][j] : 0.0f;
        }
    }
    const float* Vc = Vr + (size_t)(bh * Nc + t * Cc) * Dc;
    #pragma unroll
    for (int i = 0; i < 4; ++i) {
        int f = tid + i * 256;
        int r = f >> 4;
        int d = (f & 15) << 2;
        float4 vv = *(const float4*)&Vc[r * Dc + d];
        *(float4*)&QsT[r][d] = vv;
    }
    __syncthreads();

    for (int j = 0; j < 64; ++j) {
        float4 a = *(const float4*)&KsT[j][ty * 4];
        float4 v = *(const float4*)&QsT[j][tx * 4];
        float av[4] = {a.x, a.y, a.z, a.w};
        float vv[4] = {v.x, v.y, v.z, v.w};
        #pragma unroll
        for (int i = 0; i < 4; ++i)
            #pragma unroll
            for (int jj = 0; jj < 4; ++jj)
                accO[i][jj] = fmaf(av[i], vv[jj], accO[i][jj]);
    }

    // LayerNorm over D=64 per row (row spread across 16 tx lanes)
    #pragma unroll
    for (int i = 0; i < 4; ++i) {
        float sum = accO[i][0] + accO[i][1] + accO[i][2] + accO[i][3];
        float sq  = accO[i][0] * accO[i][0] + accO[i][1] * accO[i][1]
                  + accO[i][2] * accO[i][2] + accO[i][3] * accO[i][3];
        #pragma unroll
        for (int m = 1; m < 16; m <<= 1) {
            sum += __shfl_xor(sum, m, 64);
            sq  += __shfl_xor(sq,  m, 64);
        }
        float mean = sum * (1.0f / 64.0f);
        float var  = sq * (1.0f / 64.0f) - mean * mean;
        float rinv = rsqrtf(var + 1e-6f);
        #pragma unroll
        for (int jj = 0; jj < 4; ++jj)
            accO[i][jj] = (accO[i][jj] - mean) * rinv;
    }

    // gate multiply + hi/lo bf16 store to (B, N, E)
    #pragma unroll
    for (int i = 0; i < 4; ++i) {
        int n = t * Cc + ty * 4 + i;
        size_t idx = ((size_t)b * Nc + n) * Ec + h * Dc + tx * 4;
        float4 g = *(const float4*)&G[idx];
        float o0 = accO[i][0] * g.x, o1 = accO[i][1] * g.y;
        float o2 = accO[i][2] * g.z, o3 = accO[i][3] * g.w;
        ushort4 hh, ll;
        hh.x = f2bf(o0); ll.x = f2bf(o0 - bf2f(hh.x));
        hh.y = f2bf(o1); ll.y = f2bf(o1 - bf2f(hh.y));
        hh.z = f2bf(o2); ll.z = f2bf(o2 - bf2f(hh.z));
        hh.w = f2bf(o3); ll.w = f2bf(o3 - bf2f(hh.w));
        *(ushort4*)&retGh[idx] = hh;
        *(ushort4*)&retGl[idx] = ll;
    }
}

// ---------------------------------------------------------------------------
extern "C" void kernel_launch(void* const* d_in, const int* in_sizes, int n_in,
                              void* d_out, int out_size, void* d_ws, size_t ws_size,
                              hipStream_t stream) {
    const float* query = (const float*)d_in[0];
    const float* key   = (const float*)d_in[1];
    const float* value = (const float*)d_in[2];
    const float* Wq = (const float*)d_in[3];
    const float* bq = (const float*)d_in[4];
    const float* Wk = (const float*)d_in[5];
    const float* bk = (const float*)d_in[6];
    const float* Wv = (const float*)d_in[7];
    const float* bv = (const float*)d_in[8];
    const float* Wg = (const float*)d_in[9];
    const float* bg = (const float*)d_in[10];
    const float* Wo = (const float*)d_in[11];
    const float* bo = (const float*)d_in[12];
    float* out = (float*)d_out;

    float* wsf = (float*)d_ws;
    const size_t SZ = (size_t)Bc * Nc * Ec;   // 2,097,152

    float* Qr = wsf;                 // fp32 (B,H,N,D)
    float* Kr = Qr + SZ;
    float* Vr = Kr + SZ;
    float* G  = Vr + SZ;             // fp32 (B,N,E)

    // X hi/lo region [4SZ, 7SZ) floats — dead after fused GEMM, then reused:
    unsigned short* Xq_h = (unsigned short*)(wsf + 4 * SZ);
    unsigned short* Xq_l = Xq_h + SZ;
    unsigned short* Xk_h = Xq_l + SZ;
    unsigned short* Xk_l = Xk_h + SZ;
    unsigned short* Xv_h = Xk_l + SZ;
    unsigned short* Xv_l = Xv_h + SZ;
    float* L   = wsf + 4 * SZ;                       // overlays Xq (after GEMM)
    float* Sst = wsf + 5 * SZ;                       // overlays Xk
    unsigned short* retGh = (unsigned short*)(wsf + 6 * SZ);  // overlays Xv
    unsigned short* retGl = retGh + SZ;

    const size_t WSZ = (size_t)Ec * Ec;      // 262,144
    unsigned short* Wp = (unsigned short*)(wsf + 7 * SZ);
    unsigned short* Wq_h = Wp;            unsigned short* Wq_l = Wp + WSZ;
    unsigned short* Wk_h = Wp + 2 * WSZ;  unsigned short* Wk_l = Wp + 3 * WSZ;
    unsigned short* Wv_h = Wp + 4 * WSZ;  unsigned short* Wv_l = Wp + 5 * WSZ;
    unsigned short* Wg_h = Wp + 6 * WSZ;  unsigned short* Wg_l = Wp + 7 * WSZ;
    unsigned short* Wo_h = Wp + 8 * WSZ;  unsigned short* Wo_l = Wp + 9 * WSZ;

    float* tab = wsf + 7 * SZ + (10 * WSZ) / 2;
    float* sinS  = tab;
    float* cosS  = sinS + Nc * 32;
    float* sinIS = cosS + Nc * 32;
    float* cosIS = sinIS + Nc * 32;

    SplitArgs sa;
    sa.src[0] = query; sa.hi[0] = Xq_h; sa.lo[0] = Xq_l; sa.n[0] = (int)SZ;
    sa.src[1] = key;   sa.hi[1] = Xk_h; sa.lo[1] = Xk_l; sa.n[1] = (int)SZ;
    sa.src[2] = value; sa.hi[2] = Xv_h; sa.lo[2] = Xv_l; sa.n[2] = (int)SZ;
    sa.src[3] = Wq;    sa.hi[3] = Wq_h; sa.lo[3] = Wq_l; sa.n[3] = (int)WSZ;
    sa.src[4] = Wk;    sa.hi[4] = Wk_h; sa.lo[4] = Wk_l; sa.n[4] = (int)WSZ;
    sa.src[5] = Wv;    sa.hi[5] = Wv_h; sa.lo[5] = Wv_l; sa.n[5] = (int)WSZ;
    sa.src[6] = Wg;    sa.hi[6] = Wg_h; sa.lo[6] = Wg_l; sa.n[6] = (int)WSZ;
    sa.src[7] = Wo;    sa.hi[7] = Wo_h; sa.lo[7] = Wo_l; sa.n[7] = (int)WSZ;
    prep_kernel<<<dim3(2048, 9), dim3(256), 0, stream>>>(sa, sinS, cosS, sinIS, cosIS);

    // fused Q/K/V/G projections: 128x128 tiles, reg-B + LDS-A pipeline
    mgemm_kernel<128, 128, 2, 2><<<dim3(Mc / 128, Ec / 128, 4), dim3(256), 0, stream>>>(
        Xq_h, Xq_l, Xk_h, Xk_l, Xv_h, Xv_l, retGh, retGl,
        Wq_h, Wq_l, Wk_h, Wk_l, Wv_h, Wv_l, Wg_h, Wg_l, Wo_h, Wo_l,
        bq, bk, bv, bg, bo, Qr, Kr, Vr, G, out,
        sinS, cosS, sinIS, cosIS, 0);

    phaseA_kernel<<<dim3(Bc * Hc, NT), dim3(256), 0, stream>>>(Kr, Vr, L);
    scan_kernel<<<dim3(Bc * Hc, 4), dim3(256), 0, stream>>>(L, Sst);
    phaseC_kernel<<<dim3(Bc * Hc, NT), dim3(256), 0, stream>>>(Qr, Kr, Vr, Sst, G, retGh, retGl);

    // final: out = retG @ Wo^T + bo, 128x64 tiles, 512 threads (256 blocks)
    mgemm_kernel<128, 64, 4, 2><<<dim3(Mc / 128, Ec / 64, 1), dim3(512), 0, stream>>>(
        Xq_h, Xq_l, Xk_h, Xk_l, Xv_h, Xv_l, retGh, retGl,
        Wq_h, Wq_l, Wk_h, Wk_l, Wv_h, Wv_l, Wg_h, Wg_l, Wo_h, Wo_l,
        bq, bk, bv, bg, bo, Qr, Kr, Vr, G, out,
        sinS, cosS, sinIS, cosIS, 4);
}

// Round 6
// 189.130 us; speedup vs baseline: 1.0631x; 1.0631x over previous
//
#include <hip/hip_runtime.h>
#include <math.h>

#define Bc 2
#define Nc 2048
#define Ec 512
#define Hc 8
#define Dc 64
#define Mc 4096   // B*N
#define NT 32     // chunks per sequence
#define Cc 64     // chunk size

typedef short bf16x8 __attribute__((ext_vector_type(8)));
typedef float f32x4 __attribute__((ext_vector_type(4)));

// global -> LDS direct DMA, 16B per lane, dest = wave-uniform base + lane*16
#define GLOAD(g, l) __builtin_amdgcn_global_load_lds(                        \
    (const __attribute__((address_space(1))) unsigned*)(const void*)(g),     \
    (__attribute__((address_space(3))) unsigned*)(void*)(l), 16, 0, 0)

#define VMCNT(n) asm volatile("s_waitcnt vmcnt(" #n ")" ::: "memory")

__device__ __forceinline__ unsigned short f2bf(float x) {
    union { float f; unsigned u; } v; v.f = x;
    unsigned r = v.u + 0x7fffu + ((v.u >> 16) & 1u);   // RNE
    return (unsigned short)(r >> 16);
}
__device__ __forceinline__ float bf2f(unsigned short b) {
    union { float f; unsigned u; } v; v.u = ((unsigned)b) << 16;
    return v.f;
}

// gamma per head: 1 - exp(linspace(log(1/32), log(1/512), 8))
__device__ __forceinline__ float get_gamma(int h) {
    const float l0 = -3.4657359028f;
    const float l1 = -6.2383246250f;
    return 1.0f - expf(l0 + (l1 - l0) * ((float)h / 7.0f));
}

// ---------------------------------------------------------------------------
// split fp32 arrays into bf16 hi/lo pairs + xpos tables (transposed [32][2048]),
// one launch. IS tables have 1/sqrt(D)=0.125 folded in (K path).
struct SplitArgs {
    const float* src[8];
    unsigned short* hi[8];
    unsigned short* lo[8];
    int n[8];
};

__global__ __launch_bounds__(256) void prep_kernel(SplitArgs a,
                                                   float* __restrict__ sinS,
                                                   float* __restrict__ cosS,
                                                   float* __restrict__ sinIS,
                                                   float* __restrict__ cosIS) {
    int y = blockIdx.y;
    if (y == 8) {
        int idx = blockIdx.x * 256 + threadIdx.x;
        if (idx >= Nc * 32) return;
        int n = idx & 2047;
        int i = idx >> 11;                 // 0..31
        float xscale = (2.0f * (float)i + 25.6f) / 89.6f;
        float power  = ((float)n - 1024.0f) / 512.0f;
        float scale  = powf(xscale, power);
        float inv_freq = powf(10000.0f, -(float)i / 32.0f);
        float ang = (float)n * inv_freq;
        float s = sinf(ang), c = cosf(ang);
        int o = i * 2048 + n;              // transposed layout
        sinS[o]  = s * scale;
        cosS[o]  = c * scale;
        float rs = 0.125f / scale;         // fold K's 1/sqrt(D)
        sinIS[o] = s * rs;
        cosIS[o] = c * rs;
        return;
    }
    int i4 = (blockIdx.x * 256 + threadIdx.x) * 4;
    if (i4 >= a.n[y]) return;
    float4 v = *(const float4*)&a.src[y][i4];
    ushort4 h, l;
    h.x = f2bf(v.x); l.x = f2bf(v.x - bf2f(h.x));
    h.y = f2bf(v.y); l.y = f2bf(v.y - bf2f(h.y));
    h.z = f2bf(v.z); l.z = f2bf(v.z - bf2f(h.z));
    h.w = f2bf(v.w); l.w = f2bf(v.w - bf2f(h.w));
    *(ushort4*)&a.hi[y][i4] = h;
    *(ushort4*)&a.lo[y][i4] = l;
}

// ---------------------------------------------------------------------------
// bf16x3 MFMA GEMM, LDS-staged A and B (global_load_lds), double-buffered,
// counted vmcnt, XCD-chunked block swizzle for W-panel L2 residency.
// C[r][c] = sum_k X[r][k]*W[c][k] + bias[c]; x*w ~= xh*wh + xh*wl + xl*wh.
// TMxTN tile, wave grid WRxWC, wave tile (TM/WR)x(TN/WC).
// mode: 0=Q (xpos*scale), 1=K (xpos/scale/8 folded), 2=V, 3=G (silu), 4=final
template<int TM, int TN, int WR, int WC>
__global__ __launch_bounds__(WR * WC * 64) void mgemm_kernel(
    const unsigned short* __restrict__ Xq_h, const unsigned short* __restrict__ Xq_l,
    const unsigned short* __restrict__ Xk_h, const unsigned short* __restrict__ Xk_l,
    const unsigned short* __restrict__ Xv_h, const unsigned short* __restrict__ Xv_l,
    const unsigned short* __restrict__ Xr_h, const unsigned short* __restrict__ Xr_l,
    const unsigned short* __restrict__ Wq_h, const unsigned short* __restrict__ Wq_l,
    const unsigned short* __restrict__ Wk_h, const unsigned short* __restrict__ Wk_l,
    const unsigned short* __restrict__ Wv_h, const unsigned short* __restrict__ Wv_l,
    const unsigned short* __restrict__ Wg_h, const unsigned short* __restrict__ Wg_l,
    const unsigned short* __restrict__ Wo_h, const unsigned short* __restrict__ Wo_l,
    const float* __restrict__ bq, const float* __restrict__ bk, const float* __restrict__ bv,
    const float* __restrict__ bg, const float* __restrict__ bo,
    float* __restrict__ Qr, float* __restrict__ Kr, float* __restrict__ Vr,
    float* __restrict__ G, float* __restrict__ Out,
    const float* __restrict__ sinS, const float* __restrict__ cosS,
    const float* __restrict__ sinIS, const float* __restrict__ cosIS,
    int mode_base)
{
    constexpr int THREADS = WR * WC * 64;
    constexpr int MI  = TM / WR / 16;
    constexpr int NI  = TN / WC / 16;
    constexpr int RA  = TM * 4 / THREADS;      // A stage rounds
    constexpr int RB  = TN * 4 / THREADS;      // B stage rounds
    constexpr int GL  = 2 * (RA + RB);         // GLOADs per thread per stage
    constexpr int BUF = (TM + TN) * 64;        // shorts per K-step buffer
    constexpr int ALo = TM * 32;
    constexpr int BHo = TM * 64;
    constexpr int BLo = TM * 64 + TN * 32;
    static_assert(GL == 6 || GL == 8, "vmcnt literal");

    // XCD-chunked bijective swizzle (nwg % 8 == 0): dispatch id%8 = XCD,
    // give XCD k the contiguous chunk [k*nwg/8, (k+1)*nwg/8).
    int gx = gridDim.x, gy = gridDim.y;
    int nwg = gx * gy * gridDim.z;
    int id = blockIdx.x + gx * (blockIdx.y + gy * blockIdx.z);
    int sid = (id & 7) * (nwg >> 3) + (id >> 3);
    int bx = sid % gx; int rest = sid / gx;
    int by = rest % gy; int bz = rest / gy;

    int mode = mode_base + bz;
    const unsigned short *Xh, *Xl, *Wh, *Wl; const float* bias;
    switch (mode) {
        case 0:  Xh = Xq_h; Xl = Xq_l; Wh = Wq_h; Wl = Wq_l; bias = bq; break;
        case 1:  Xh = Xk_h; Xl = Xk_l; Wh = Wk_h; Wl = Wk_l; bias = bk; break;
        case 2:  Xh = Xv_h; Xl = Xv_l; Wh = Wv_h; Wl = Wv_l; bias = bv; break;
        case 3:  Xh = Xq_h; Xl = Xq_l; Wh = Wg_h; Wl = Wg_l; bias = bg; break;
        default: Xh = Xr_h; Xl = Xr_l; Wh = Wo_h; Wl = Wo_l; bias = bo; break;
    }

    __shared__ __align__(16) short lds[2 * BUF];

    int tid  = threadIdx.x;
    int lane = tid & 63;
    int w    = tid >> 6;
    int wr   = w / WC, wc = w % WC;
    int row0 = bx * TM, col0 = by * TN;
    int lrow = lane & 15, lslot = lane >> 4;

    f32x4 acc[MI][NI];
    #pragma unroll
    for (int i = 0; i < MI; ++i)
        #pragma unroll
        for (int j = 0; j < NI; ++j) acc[i][j] = {0.f, 0.f, 0.f, 0.f};

    int aoff[MI], boff[NI];
    #pragma unroll
    for (int mi = 0; mi < MI; ++mi) {
        int r = wr * (TM / WR) + mi * 16 + lrow;
        aoff[mi] = (r * 4 + (lslot ^ ((r >> 1) & 3))) * 8;
    }
    #pragma unroll
    for (int ni = 0; ni < NI; ++ni) {
        int r = wc * (TN / WC) + ni * 16 + lrow;
        boff[ni] = (r * 4 + (lslot ^ ((r >> 1) & 3))) * 8;
    }

    // stage one K-step tile (A then B), slot-linear dest, pre-swizzled source
    auto stage = [&](int buf, int k0) {
        short* l = &lds[buf * BUF];
        #pragma unroll
        for (int i = 0; i < RA; ++i) {
            int q = i * THREADS + tid;
            int r = q >> 2;
            int sp = (q & 3) ^ ((r >> 1) & 3);
            int base = (i * THREADS + (w << 6)) * 8;
            size_t ga = (size_t)(row0 + r) * Ec + k0 + sp * 8;
            GLOAD(Xh + ga, &l[base]);
            GLOAD(Xl + ga, &l[ALo + base]);
        }
        #pragma unroll
        for (int i = 0; i < RB; ++i) {
            int q = i * THREADS + tid;
            int r = q >> 2;
            int sp = (q & 3) ^ ((r >> 1) & 3);
            int base = (i * THREADS + (w << 6)) * 8;
            size_t gb = (size_t)(col0 + r) * Ec + k0 + sp * 8;
            GLOAD(Wh + gb, &l[BHo + base]);
            GLOAD(Wl + gb, &l[BLo + base]);
        }
    };

    stage(0, 0);
    for (int t = 0; t < Ec / 32; ++t) {
        int cur = t & 1;
        if (t < Ec / 32 - 1) {
            stage(cur ^ 1, (t + 1) * 32);
            // wait tile-t loads only; just-issued prefetch stays in flight
            if constexpr (GL == 6) VMCNT(6); else VMCNT(8);
        } else {
            VMCNT(0);
        }
        __builtin_amdgcn_s_barrier();
        __builtin_amdgcn_sched_barrier(0);

        const short* l = &lds[cur * BUF];
        bf16x8 ah[MI], al[MI], bh[NI], bl[NI];
        #pragma unroll
        for (int mi = 0; mi < MI; ++mi) {
            ah[mi] = *(const bf16x8*)&l[aoff[mi]];
            al[mi] = *(const bf16x8*)&l[ALo + aoff[mi]];
        }
        #pragma unroll
        for (int ni = 0; ni < NI; ++ni) {
            bh[ni] = *(const bf16x8*)&l[BHo + boff[ni]];
            bl[ni] = *(const bf16x8*)&l[BLo + boff[ni]];
        }
        #pragma unroll
        for (int mi = 0; mi < MI; ++mi)
            #pragma unroll
            for (int ni = 0; ni < NI; ++ni) {
                acc[mi][ni] = __builtin_amdgcn_mfma_f32_16x16x32_bf16(ah[mi], bh[ni], acc[mi][ni], 0, 0, 0);
                acc[mi][ni] = __builtin_amdgcn_mfma_f32_16x16x32_bf16(ah[mi], bl[ni], acc[mi][ni], 0, 0, 0);
                acc[mi][ni] = __builtin_amdgcn_mfma_f32_16x16x32_bf16(al[mi], bh[ni], acc[mi][ni], 0, 0, 0);
            }
        asm volatile("s_waitcnt lgkmcnt(0)" ::: "memory");
        __builtin_amdgcn_sched_barrier(0);
        __builtin_amdgcn_s_barrier();
    }

    // epilogue: D[row][col]: col = lane&15, row = (lane>>4)*4 + reg
    int quad = lslot;
    if (mode <= 1) {
        const float* st = (mode == 0) ? sinS : sinIS;
        const float* ct = (mode == 0) ? cosS : cosIS;
        float* dst = (mode == 0) ? Qr : Kr;
        #pragma unroll
        for (int ni = 0; ni < NI; ++ni) {
            int c = col0 + wc * (TN / WC) + ni * 16 + lrow;
            int h = c >> 6, d = c & 63, pr = d >> 1;
            float bi = bias[c];
            #pragma unroll
            for (int mi = 0; mi < MI; ++mi) {
                int R0 = row0 + wr * (TM / WR) + mi * 16 + quad * 4;
                int bb = R0 >> 11;
                int n0 = R0 & 2047;
                float4 sv4 = *(const float4*)&st[pr * 2048 + n0];
                float4 cv4 = *(const float4*)&ct[pr * 2048 + n0];
                float svv[4] = {sv4.x, sv4.y, sv4.z, sv4.w};
                float cvv[4] = {cv4.x, cv4.y, cv4.z, cv4.w};
                #pragma unroll
                for (int reg = 0; reg < 4; ++reg) {
                    float x = acc[mi][ni][reg] + bi;
                    float p = __shfl_xor(x, 1, 64);       // partner column c^1
                    float y = (c & 1) ? fmaf(x, cvv[reg],  p * svv[reg])
                                      : fmaf(x, cvv[reg], -p * svv[reg]);
                    dst[(((size_t)(bb * Hc + h)) * Nc + n0 + reg) * Dc + d] = y;
                }
            }
        }
    } else if (mode == 2) {
        #pragma unroll
        for (int ni = 0; ni < NI; ++ni) {
            int c = col0 + wc * (TN / WC) + ni * 16 + lrow;
            int h = c >> 6, d = c & 63;
            float bi = bias[c];
            #pragma unroll
            for (int mi = 0; mi < MI; ++mi) {
                int R0 = row0 + wr * (TM / WR) + mi * 16 + quad * 4;
                int bb = R0 >> 11;
                int n0 = R0 & 2047;
                #pragma unroll
                for (int reg = 0; reg < 4; ++reg)
                    Vr[(((size_t)(bb * Hc + h)) * Nc + n0 + reg) * Dc + d] =
                        acc[mi][ni][reg] + bi;
            }
        }
    } else {
        #pragma unroll
        for (int ni = 0; ni < NI; ++ni) {
            int c = col0 + wc * (TN / WC) + ni * 16 + lrow;
            float bi = bias[c];
            #pragma unroll
            for (int mi = 0; mi < MI; ++mi) {
                int R0 = row0 + wr * (TM / WR) + mi * 16 + quad * 4;
                #pragma unroll
                for (int reg = 0; reg < 4; ++reg) {
                    float x = acc[mi][ni][reg] + bi;
                    if (mode == 3)
                        G[(size_t)(R0 + reg) * Ec + c] = x / (1.0f + expf(-x));
                    else
                        Out[(size_t)(R0 + reg) * Ec + c] = x;
                }
            }
        }
    }
}

// ---------------------------------------------------------------------------
// Phase A: per (bh, chunk) local state  L[dk][dv] = sum_s gamma^(64-s) K[s][dk] V[s][dv]
__global__ __launch_bounds__(256) void phaseA_kernel(const float* __restrict__ Kr,
                                                     const float* __restrict__ Vr,
                                                     float* __restrict__ L)
{
    int bh = blockIdx.x;
    int t  = blockIdx.y;
    float gamma = get_gamma(bh & 7);
    float lg = logf(gamma);

    __shared__ float Ks[64][68];
    __shared__ float Vs[64][68];

    int tid = threadIdx.x;
    const float* Kc = Kr + (size_t)(bh * Nc + t * Cc) * Dc;
    const float* Vc = Vr + (size_t)(bh * Nc + t * Cc) * Dc;

    #pragma unroll
    for (int i = 0; i < 4; ++i) {
        int f = tid + i * 256;
        int s = f >> 4;
        int d = (f & 15) << 2;
        float w = expf(lg * (float)(Cc - s));
        float4 kv = *(const float4*)&Kc[s * Dc + d];
        float4 ks = {kv.x * w, kv.y * w, kv.z * w, kv.w * w};
        *(float4*)&Ks[s][d] = ks;
        float4 vv = *(const float4*)&Vc[s * Dc + d];
        *(float4*)&Vs[s][d] = vv;
    }
    __syncthreads();

    int tx = tid & 15, ty = tid >> 4;
    float acc[4][4];
    #pragma unroll
    for (int i = 0; i < 4; ++i)
        #pragma unroll
        for (int j = 0; j < 4; ++j) acc[i][j] = 0.0f;

    for (int s = 0; s < 64; ++s) {
        float4 a = *(const float4*)&Ks[s][ty * 4];
        float4 b = *(const float4*)&Vs[s][tx * 4];
        float av[4] = {a.x, a.y, a.z, a.w};
        float bv[4] = {b.x, b.y, b.z, b.w};
        #pragma unroll
        for (int i = 0; i < 4; ++i)
            #pragma unroll
            for (int j = 0; j < 4; ++j)
                acc[i][j] = fmaf(av[i], bv[j], acc[i][j]);
    }

    float* Lp = L + (size_t)(bh * NT + t) * 4096;
    #pragma unroll
    for (int i = 0; i < 4; ++i) {
        float4 o = {acc[i][0], acc[i][1], acc[i][2], acc[i][3]};
        *(float4*)&Lp[(ty * 4 + i) * 64 + tx * 4] = o;
    }
}

// ---------------------------------------------------------------------------
// Phase B: S_0 = 0 ; S_{t+1} = gamma^64 * S_t + L_t  (S_t written pre-fold)
// grid (16, 4): each block owns one 1024-float quarter of the 64x64 state.
__global__ __launch_bounds__(256) void scan_kernel(const float* __restrict__ L,
                                                   float* __restrict__ Sst)
{
    int bh = blockIdx.x;
    int part = blockIdx.y;
    int tid = threadIdx.x;
    float gamma = get_gamma(bh & 7);
    float g64 = expf(logf(gamma) * 64.0f);

    float4 s = {0.0f, 0.0f, 0.0f, 0.0f};
    size_t base = (size_t)bh * NT * 4096 + part * 1024 + tid * 4;
    const float* Lp = L + base;
    float* Sp = Sst + base;
    for (int t = 0; t < NT; ++t) {
        *(float4*)&Sp[(size_t)t * 4096] = s;
        float4 l = *(const float4*)&Lp[(size_t)t * 4096];
        s.x = s.x * g64 + l.x;
        s.y = s.y * g64 + l.y;
        s.z = s.z * g64 + l.z;
        s.w = s.w * g64 + l.w;
    }
}

// ---------------------------------------------------------------------------
// Phase C: O = tril-decayed(QK^T) @ V + gamma^i * Q @ S, LayerNorm, gate,
// write retG as bf16 hi/lo in (B,N,E) layout.
__global__ __launch_bounds__(256) void phaseC_kernel(
    const float* __restrict__ Qr, const float* __restrict__ Kr, const float* __restrict__ Vr,
    const float* __restrict__ Sst, const float* __restrict__ G,
    unsigned short* __restrict__ retGh, unsigned short* __restrict__ retGl)
{
    int bh = blockIdx.x, t = blockIdx.y;
    int b = bh >> 3, h = bh & 7;
    float gamma = get_gamma(h);
    float lg = logf(gamma);

    __shared__ float QsT[64][68];
    __shared__ float KsT[64][68];
    __shared__ float Ss[64][68];

    int tid = threadIdx.x;
    const float* Qc = Qr + (size_t)(bh * Nc + t * Cc) * Dc;
    const float* Kc = Kr + (size_t)(bh * Nc + t * Cc) * Dc;
    const float* Sp = Sst + (size_t)(bh * NT + t) * 4096;

    #pragma unroll
    for (int i = 0; i < 4; ++i) {
        int f = tid + i * 256;
        int r = f >> 4;
        int d = (f & 15) << 2;
        float wq = expf(lg * (float)r);
        float4 q = *(const float4*)&Qc[r * Dc + d];
        QsT[d + 0][r] = q.x * wq; QsT[d + 1][r] = q.y * wq;
        QsT[d + 2][r] = q.z * wq; QsT[d + 3][r] = q.w * wq;
        float wk = expf(-lg * (float)r);
        float4 kk = *(const float4*)&Kc[r * Dc + d];
        KsT[d + 0][r] = kk.x * wk; KsT[d + 1][r] = kk.y * wk;
        KsT[d + 2][r] = kk.z * wk; KsT[d + 3][r] = kk.w * wk;
        float4 sv = *(const float4*)&Sp[r * 64 + d];
        *(float4*)&Ss[r][d] = sv;
    }
    __syncthreads();

    int tx = tid & 15, ty = tid >> 4;
    float accA[4][4], accO[4][4];
    #pragma unroll
    for (int i = 0; i < 4; ++i)
        #pragma unroll
        for (int j = 0; j < 4; ++j) { accA[i][j] = 0.0f; accO[i][j] = 0.0f; }

    for (int d = 0; d < 64; ++d) {
        float4 a  = *(const float4*)&QsT[d][ty * 4];
        float4 kb = *(const float4*)&KsT[d][tx * 4];
        float4 sb = *(const float4*)&Ss[d][tx * 4];
        float av[4] = {a.x, a.y, a.z, a.w};
        float kv[4] = {kb.x, kb.y, kb.z, kb.w};
        float sv[4] = {sb.x, sb.y, sb.z, sb.w};
        #pragma unroll
        for (int i = 0; i < 4; ++i)
            #pragma unroll
            for (int j = 0; j < 4; ++j) {
                accA[i][j] = fmaf(av[i], kv[j], accA[i][j]);
                accO[i][j] = fmaf(av[i], sv[j], accO[i][j]);
            }
    }
    __syncthreads();

    #pragma unroll
    for (int i = 0; i < 4; ++i) {
        int gi = ty * 4 + i;
        #pragma unroll
        for (int j = 0; j < 4; ++j) {
            int gj = tx * 4 + j;
            KsT[gj][gi] = (gj <= gi) ? accA[i][j] : 0.0f;
        }
    }
    const float* Vc = Vr + (size_t)(bh * Nc + t * Cc) * Dc;
    #pragma unroll
    for (int i = 0; i < 4; ++i) {
        int f = tid + i * 256;
        int r = f >> 4;
        int d = (f & 15) << 2;
        float4 vv = *(const float4*)&Vc[r * Dc + d];
        *(float4*)&QsT[r][d] = vv;
    }
    __syncthreads();

    for (int j = 0; j < 64; ++j) {
        float4 a = *(const float4*)&KsT[j][ty * 4];
        float4 v = *(const float4*)&QsT[j][tx * 4];
        float av[4] = {a.x, a.y, a.z, a.w};
        float vv[4] = {v.x, v.y, v.z, v.w};
        #pragma unroll
        for (int i = 0; i < 4; ++i)
            #pragma unroll
            for (int jj = 0; jj < 4; ++jj)
                accO[i][jj] = fmaf(av[i], vv[jj], accO[i][jj]);
    }

    // LayerNorm over D=64 per row (row spread across 16 tx lanes)
    #pragma unroll
    for (int i = 0; i < 4; ++i) {
        float sum = accO[i][0] + accO[i][1] + accO[i][2] + accO[i][3];
        float sq  = accO[i][0] * accO[i][0] + accO[i][1] * accO[i][1]
                  + accO[i][2] * accO[i][2] + accO[i][3] * accO[i][3];
        #pragma unroll
        for (int m = 1; m < 16; m <<= 1) {
            sum += __shfl_xor(sum, m, 64);
            sq  += __shfl_xor(sq,  m, 64);
        }
        float mean = sum * (1.0f / 64.0f);
        float var  = sq * (1.0f / 64.0f) - mean * mean;
        float rinv = rsqrtf(var + 1e-6f);
        #pragma unroll
        for (int jj = 0; jj < 4; ++jj)
            accO[i][jj] = (accO[i][jj] - mean) * rinv;
    }

    // gate multiply + hi/lo bf16 store to (B, N, E)
    #pragma unroll
    for (int i = 0; i < 4; ++i) {
        int n = t * Cc + ty * 4 + i;
        size_t idx = ((size_t)b * Nc + n) * Ec + h * Dc + tx * 4;
        float4 g = *(const float4*)&G[idx];
        float o0 = accO[i][0] * g.x, o1 = accO[i][1] * g.y;
        float o2 = accO[i][2] * g.z, o3 = accO[i][3] * g.w;
        ushort4 hh, ll;
        hh.x = f2bf(o0); ll.x = f2bf(o0 - bf2f(hh.x));
        hh.y = f2bf(o1); ll.y = f2bf(o1 - bf2f(hh.y));
        hh.z = f2bf(o2); ll.z = f2bf(o2 - bf2f(hh.z));
        hh.w = f2bf(o3); ll.w = f2bf(o3 - bf2f(hh.w));
        *(ushort4*)&retGh[idx] = hh;
        *(ushort4*)&retGl[idx] = ll;
    }
}

// ---------------------------------------------------------------------------
extern "C" void kernel_launch(void* const* d_in, const int* in_sizes, int n_in,
                              void* d_out, int out_size, void* d_ws, size_t ws_size,
                              hipStream_t stream) {
    const float* query = (const float*)d_in[0];
    const float* key   = (const float*)d_in[1];
    const float* value = (const float*)d_in[2];
    const float* Wq = (const float*)d_in[3];
    const float* bq = (const float*)d_in[4];
    const float* Wk = (const float*)d_in[5];
    const float* bk = (const float*)d_in[6];
    const float* Wv = (const float*)d_in[7];
    const float* bv = (const float*)d_in[8];
    const float* Wg = (const float*)d_in[9];
    const float* bg = (const float*)d_in[10];
    const float* Wo = (const float*)d_in[11];
    const float* bo = (const float*)d_in[12];
    float* out = (float*)d_out;

    float* wsf = (float*)d_ws;
    const size_t SZ = (size_t)Bc * Nc * Ec;   // 2,097,152

    float* Qr = wsf;                 // fp32 (B,H,N,D)
    float* Kr = Qr + SZ;
    float* Vr = Kr + SZ;
    float* G  = Vr + SZ;             // fp32 (B,N,E)

    // X hi/lo region [4SZ, 7SZ) floats — dead after fused GEMM, then reused:
    unsigned short* Xq_h = (unsigned short*)(wsf + 4 * SZ);
    unsigned short* Xq_l = Xq_h + SZ;
    unsigned short* Xk_h = Xq_l + SZ;
    unsigned short* Xk_l = Xk_h + SZ;
    unsigned short* Xv_h = Xk_l + SZ;
    unsigned short* Xv_l = Xv_h + SZ;
    float* L   = wsf + 4 * SZ;                       // overlays Xq (after GEMM)
    float* Sst = wsf + 5 * SZ;                       // overlays Xk
    unsigned short* retGh = (unsigned short*)(wsf + 6 * SZ);  // overlays Xv
    unsigned short* retGl = retGh + SZ;

    const size_t WSZ = (size_t)Ec * Ec;      // 262,144
    unsigned short* Wp = (unsigned short*)(wsf + 7 * SZ);
    unsigned short* Wq_h = Wp;            unsigned short* Wq_l = Wp + WSZ;
    unsigned short* Wk_h = Wp + 2 * WSZ;  unsigned short* Wk_l = Wp + 3 * WSZ;
    unsigned short* Wv_h = Wp + 4 * WSZ;  unsigned short* Wv_l = Wp + 5 * WSZ;
    unsigned short* Wg_h = Wp + 6 * WSZ;  unsigned short* Wg_l = Wp + 7 * WSZ;
    unsigned short* Wo_h = Wp + 8 * WSZ;  unsigned short* Wo_l = Wp + 9 * WSZ;

    float* tab = wsf + 7 * SZ + (10 * WSZ) / 2;
    float* sinS  = tab;
    float* cosS  = sinS + Nc * 32;
    float* sinIS = cosS + Nc * 32;
    float* cosIS = sinIS + Nc * 32;

    SplitArgs sa;
    sa.src[0] = query; sa.hi[0] = Xq_h; sa.lo[0] = Xq_l; sa.n[0] = (int)SZ;
    sa.src[1] = key;   sa.hi[1] = Xk_h; sa.lo[1] = Xk_l; sa.n[1] = (int)SZ;
    sa.src[2] = value; sa.hi[2] = Xv_h; sa.lo[2] = Xv_l; sa.n[2] = (int)SZ;
    sa.src[3] = Wq;    sa.hi[3] = Wq_h; sa.lo[3] = Wq_l; sa.n[3] = (int)WSZ;
    sa.src[4] = Wk;    sa.hi[4] = Wk_h; sa.lo[4] = Wk_l; sa.n[4] = (int)WSZ;
    sa.src[5] = Wv;    sa.hi[5] = Wv_h; sa.lo[5] = Wv_l; sa.n[5] = (int)WSZ;
    sa.src[6] = Wg;    sa.hi[6] = Wg_h; sa.lo[6] = Wg_l; sa.n[6] = (int)WSZ;
    sa.src[7] = Wo;    sa.hi[7] = Wo_h; sa.lo[7] = Wo_l; sa.n[7] = (int)WSZ;
    prep_kernel<<<dim3(2048, 9), dim3(256), 0, stream>>>(sa, sinS, cosS, sinIS, cosIS);

    // fused Q/K/V/G projections: 128x256 tiles, 512 threads, 256 blocks (1/CU),
    // XCD-chunked swizzle -> W panel (512KB) L2-resident per XCD.
    mgemm_kernel<128, 256, 2, 4><<<dim3(Mc / 128, Ec / 256, 4), dim3(512), 0, stream>>>(
        Xq_h, Xq_l, Xk_h, Xk_l, Xv_h, Xv_l, retGh, retGl,
        Wq_h, Wq_l, Wk_h, Wk_l, Wv_h, Wv_l, Wg_h, Wg_l, Wo_h, Wo_l,
        bq, bk, bv, bg, bo, Qr, Kr, Vr, G, out,
        sinS, cosS, sinIS, cosIS, 0);

    phaseA_kernel<<<dim3(Bc * Hc, NT), dim3(256), 0, stream>>>(Kr, Vr, L);
    scan_kernel<<<dim3(Bc * Hc, 4), dim3(256), 0, stream>>>(L, Sst);
    phaseC_kernel<<<dim3(Bc * Hc, NT), dim3(256), 0, stream>>>(Qr, Kr, Vr, Sst, G, retGh, retGl);

    // final: out = retG @ Wo^T + bo, 128x128 tiles, 128 blocks + swizzle
    mgemm_kernel<128, 128, 2, 2><<<dim3(Mc / 128, Ec / 128, 1), dim3(256), 0, stream>>>(
        Xq_h, Xq_l, Xk_h, Xk_l, Xv_h, Xv_l, retGh, retGl,
        Wq_h, Wq_l, Wk_h, Wk_l, Wv_h, Wv_l, Wg_h, Wg_l, Wo_h, Wo_l,
        bq, bk, bv, bg, bo, Qr, Kr, Vr, G, out,
        sinS, cosS, sinIS, cosIS, 4);
}

// Round 7
// 178.084 us; speedup vs baseline: 1.1291x; 1.0620x over previous
//
#include <hip/hip_runtime.h>
#include <math.h>

#define Bc 2
#define Nc 2048
#define Ec 512
#define Hc 8
#define Dc 64
#define Mc 4096   // B*N
#define NT 32     // chunks per sequence
#define Cc 64     // chunk size

typedef short bf16x8 __attribute__((ext_vector_type(8)));
typedef float f32x4 __attribute__((ext_vector_type(4)));

// global -> LDS direct DMA, 16B per lane, dest = wave-uniform base + lane*16
#define GLOAD(g, l) __builtin_amdgcn_global_load_lds(                        \
    (const __attribute__((address_space(1))) unsigned*)(const void*)(g),     \
    (__attribute__((address_space(3))) unsigned*)(void*)(l), 16, 0, 0)

#define VMCNT(n) asm volatile("s_waitcnt vmcnt(" #n ")" ::: "memory")

__device__ __forceinline__ unsigned short f2bf(float x) {
    union { float f; unsigned u; } v; v.f = x;
    unsigned r = v.u + 0x7fffu + ((v.u >> 16) & 1u);   // RNE
    return (unsigned short)(r >> 16);
}
__device__ __forceinline__ float bf2f(unsigned short b) {
    union { float f; unsigned u; } v; v.u = ((unsigned)b) << 16;
    return v.f;
}

// gamma per head: 1 - exp(linspace(log(1/32), log(1/512), 8))
__device__ __forceinline__ float get_gamma(int h) {
    const float l0 = -3.4657359028f;
    const float l1 = -6.2383246250f;
    return 1.0f - expf(l0 + (l1 - l0) * ((float)h / 7.0f));
}

// ---------------------------------------------------------------------------
// split fp32 arrays into bf16 hi/lo pairs + xpos tables (transposed [32][2048]),
// one launch. IS tables have 1/sqrt(D)=0.125 folded in (K path).
struct SplitArgs {
    const float* src[8];
    unsigned short* hi[8];
    unsigned short* lo[8];
    int n[8];
};

__global__ __launch_bounds__(256) void prep_kernel(SplitArgs a,
                                                   float* __restrict__ sinS,
                                                   float* __restrict__ cosS,
                                                   float* __restrict__ sinIS,
                                                   float* __restrict__ cosIS) {
    int y = blockIdx.y;
    if (y == 8) {
        int idx = blockIdx.x * 256 + threadIdx.x;
        if (idx >= Nc * 32) return;
        int n = idx & 2047;
        int i = idx >> 11;                 // 0..31
        float xscale = (2.0f * (float)i + 25.6f) / 89.6f;
        float power  = ((float)n - 1024.0f) / 512.0f;
        float scale  = powf(xscale, power);
        float inv_freq = powf(10000.0f, -(float)i / 32.0f);
        float ang = (float)n * inv_freq;
        float s = sinf(ang), c = cosf(ang);
        int o = i * 2048 + n;              // transposed layout
        sinS[o]  = s * scale;
        cosS[o]  = c * scale;
        float rs = 0.125f / scale;         // fold K's 1/sqrt(D)
        sinIS[o] = s * rs;
        cosIS[o] = c * rs;
        return;
    }
    int i4 = (blockIdx.x * 256 + threadIdx.x) * 4;
    if (i4 >= a.n[y]) return;
    float4 v = *(const float4*)&a.src[y][i4];
    ushort4 h, l;
    h.x = f2bf(v.x); l.x = f2bf(v.x - bf2f(h.x));
    h.y = f2bf(v.y); l.y = f2bf(v.y - bf2f(h.y));
    h.z = f2bf(v.z); l.z = f2bf(v.z - bf2f(h.z));
    h.w = f2bf(v.w); l.w = f2bf(v.w - bf2f(h.w));
    *(ushort4*)&a.hi[y][i4] = h;
    *(ushort4*)&a.lo[y][i4] = l;
}

// ---------------------------------------------------------------------------
// bf16x3 MFMA GEMM, 4-phase interleaved schedule (m201-style), tri-buffered
// LDS, staging 2 tiles ahead, counted vmcnt(6) once per K-step (never 0 in
// steady state), setprio around MFMA clusters, XCD-chunked block swizzle.
// C[r][c] = sum_k X[r][k]*W[c][k] + bias[c]; x*w ~= xh*wh + xh*wl + xl*wh.
// mode: 0=Q (xpos*scale), 1=K (xpos/scale/8 folded), 2=V, 3=G (silu), 4=final
template<int TM, int TN, int WR, int WC>
__global__ __launch_bounds__(WR * WC * 64) void mgemm_kernel(
    const unsigned short* __restrict__ Xq_h, const unsigned short* __restrict__ Xq_l,
    const unsigned short* __restrict__ Xk_h, const unsigned short* __restrict__ Xk_l,
    const unsigned short* __restrict__ Xv_h, const unsigned short* __restrict__ Xv_l,
    const unsigned short* __restrict__ Xr_h, const unsigned short* __restrict__ Xr_l,
    const unsigned short* __restrict__ Wq_h, const unsigned short* __restrict__ Wq_l,
    const unsigned short* __restrict__ Wk_h, const unsigned short* __restrict__ Wk_l,
    const unsigned short* __restrict__ Wv_h, const unsigned short* __restrict__ Wv_l,
    const unsigned short* __restrict__ Wg_h, const unsigned short* __restrict__ Wg_l,
    const unsigned short* __restrict__ Wo_h, const unsigned short* __restrict__ Wo_l,
    const float* __restrict__ bq, const float* __restrict__ bk, const float* __restrict__ bv,
    const float* __restrict__ bg, const float* __restrict__ bo,
    float* __restrict__ Qr, float* __restrict__ Kr, float* __restrict__ Vr,
    float* __restrict__ G, float* __restrict__ Out,
    const float* __restrict__ sinS, const float* __restrict__ cosS,
    const float* __restrict__ sinIS, const float* __restrict__ cosIS,
    int mode_base)
{
    constexpr int THREADS = WR * WC * 64;
    constexpr int MI  = TM / WR / 16;
    constexpr int NI  = TN / WC / 16;
    constexpr int RA  = TM * 4 / THREADS;      // A stage rounds
    constexpr int RB  = TN * 4 / THREADS;      // B stage rounds
    constexpr int BUF = (TM + TN) * 64;        // shorts per K-step buffer
    constexpr int ALo = TM * 32;
    constexpr int BHo = TM * 64;
    constexpr int BLo = TM * 64 + TN * 32;
    constexpr int NSTEP = Ec / 32;
    static_assert(RA == 1 && RB == 2 && NI == 4, "phase schedule assumes this shape");

    // XCD-chunked bijective swizzle (nwg % 8 == 0)
    int gx = gridDim.x, gy = gridDim.y;
    int nwg = gx * gy * gridDim.z;
    int id = blockIdx.x + gx * (blockIdx.y + gy * blockIdx.z);
    int sid = (id & 7) * (nwg >> 3) + (id >> 3);
    int bx = sid % gx; int rest = sid / gx;
    int by = rest % gy; int bz = rest / gy;

    int mode = mode_base + bz;
    const unsigned short *Xh, *Xl, *Wh, *Wl; const float* bias;
    switch (mode) {
        case 0:  Xh = Xq_h; Xl = Xq_l; Wh = Wq_h; Wl = Wq_l; bias = bq; break;
        case 1:  Xh = Xk_h; Xl = Xk_l; Wh = Wk_h; Wl = Wk_l; bias = bk; break;
        case 2:  Xh = Xv_h; Xl = Xv_l; Wh = Wv_h; Wl = Wv_l; bias = bv; break;
        case 3:  Xh = Xq_h; Xl = Xq_l; Wh = Wg_h; Wl = Wg_l; bias = bg; break;
        default: Xh = Xr_h; Xl = Xr_l; Wh = Wo_h; Wl = Wo_l; bias = bo; break;
    }

    __shared__ __align__(16) short lds[3 * BUF];

    int tid  = threadIdx.x;
    int lane = tid & 63;
    int w    = tid >> 6;
    int wr   = w / WC, wc = w % WC;
    int row0 = bx * TM, col0 = by * TN;
    int lrow = lane & 15, lslot = lane >> 4;

    f32x4 acc[MI][NI];
    #pragma unroll
    for (int i = 0; i < MI; ++i)
        #pragma unroll
        for (int j = 0; j < NI; ++j) acc[i][j] = {0.f, 0.f, 0.f, 0.f};

    int aoff[MI], boff[NI];
    #pragma unroll
    for (int mi = 0; mi < MI; ++mi) {
        int r = wr * (TM / WR) + mi * 16 + lrow;
        aoff[mi] = (r * 4 + (lslot ^ ((r >> 1) & 3))) * 8;
    }
    #pragma unroll
    for (int ni = 0; ni < NI; ++ni) {
        int r = wc * (TN / WC) + ni * 16 + lrow;
        boff[ni] = (r * 4 + (lslot ^ ((r >> 1) & 3))) * 8;
    }

    // full-tile stage (prologue only): 6 GLOADs per thread
    auto stage_full = [&](int buf, int k0) {
        short* l = &lds[buf * BUF];
        {
            int q = tid;
            int r = q >> 2;
            int sp = (q & 3) ^ ((r >> 1) & 3);
            int base = (w << 6) * 8;
            size_t ga = (size_t)(row0 + r) * Ec + k0 + sp * 8;
            GLOAD(Xh + ga, &l[base]);
            GLOAD(Xl + ga, &l[ALo + base]);
        }
        #pragma unroll
        for (int i = 0; i < RB; ++i) {
            int q = i * THREADS + tid;
            int r = q >> 2;
            int sp = (q & 3) ^ ((r >> 1) & 3);
            int base = (i * THREADS + (w << 6)) * 8;
            size_t gb = (size_t)(col0 + r) * Ec + k0 + sp * 8;
            GLOAD(Wh + gb, &l[BHo + base]);
            GLOAD(Wl + gb, &l[BLo + base]);
        }
    };
    // per-phase stage portion: p0 -> A (2 loads), p1/p2 -> B rounds (2 each)
    auto stage_portion = [&](int buf, int k0, int p) {
        short* l = &lds[buf * BUF];
        if (p == 0) {
            int q = tid;
            int r = q >> 2;
            int sp = (q & 3) ^ ((r >> 1) & 3);
            int base = (w << 6) * 8;
            size_t ga = (size_t)(row0 + r) * Ec + k0 + sp * 8;
            GLOAD(Xh + ga, &l[base]);
            GLOAD(Xl + ga, &l[ALo + base]);
        } else if (p <= 2) {
            int i = p - 1;
            int q = i * THREADS + tid;
            int r = q >> 2;
            int sp = (q & 3) ^ ((r >> 1) & 3);
            int base = (i * THREADS + (w << 6)) * 8;
            size_t gb = (size_t)(col0 + r) * Ec + k0 + sp * 8;
            GLOAD(Wh + gb, &l[BHo + base]);
            GLOAD(Wl + gb, &l[BLo + base]);
        }
    };

    // prologue: tiles 0 and 1 staged; wait tile 0 (tile 1's 6 stay in flight)
    stage_full(0, 0);
    stage_full(1, 32);
    VMCNT(6);
    __builtin_amdgcn_s_barrier();

    bf16x8 ah[MI], al[MI];
    for (int t = 0; t < NSTEP; ++t) {
        const int cur = t % 3;
        const short* l = &lds[cur * BUF];
        const bool pre = (t + 2) < NSTEP;
        const int nb = (t + 2) % 3;
        const int nk = (t + 2) * 32;
        #pragma unroll
        for (int p = 0; p < 4; ++p) {
            if (p == 0) {
                #pragma unroll
                for (int mi = 0; mi < MI; ++mi) {
                    ah[mi] = *(const bf16x8*)&l[aoff[mi]];
                    al[mi] = *(const bf16x8*)&l[ALo + aoff[mi]];
                }
            }
            bf16x8 bh2 = *(const bf16x8*)&l[BHo + boff[p]];
            bf16x8 bl2 = *(const bf16x8*)&l[BLo + boff[p]];
            if (pre) stage_portion(nb, nk, p);
            __builtin_amdgcn_s_barrier();
            asm volatile("s_waitcnt lgkmcnt(0)" ::: "memory");
            __builtin_amdgcn_sched_barrier(0);
            __builtin_amdgcn_s_setprio(1);
            #pragma unroll
            for (int mi = 0; mi < MI; ++mi) {
                acc[mi][p] = __builtin_amdgcn_mfma_f32_16x16x32_bf16(ah[mi], bh2, acc[mi][p], 0, 0, 0);
                acc[mi][p] = __builtin_amdgcn_mfma_f32_16x16x32_bf16(ah[mi], bl2, acc[mi][p], 0, 0, 0);
                acc[mi][p] = __builtin_amdgcn_mfma_f32_16x16x32_bf16(al[mi], bh2, acc[mi][p], 0, 0, 0);
            }
            __builtin_amdgcn_s_setprio(0);
            if (p == 3) { if (pre) VMCNT(6); else VMCNT(0); }
            __builtin_amdgcn_s_barrier();
        }
    }

    // epilogue: D[row][col]: col = lane&15, row = (lane>>4)*4 + reg
    int quad = lslot;
    if (mode <= 1) {
        const float* st = (mode == 0) ? sinS : sinIS;
        const float* ct = (mode == 0) ? cosS : cosIS;
        float* dst = (mode == 0) ? Qr : Kr;
        #pragma unroll
        for (int ni = 0; ni < NI; ++ni) {
            int c = col0 + wc * (TN / WC) + ni * 16 + lrow;
            int h = c >> 6, d = c & 63, pr = d >> 1;
            float bi = bias[c];
            #pragma unroll
            for (int mi = 0; mi < MI; ++mi) {
                int R0 = row0 + wr * (TM / WR) + mi * 16 + quad * 4;
                int bb = R0 >> 11;
                int n0 = R0 & 2047;
                float4 sv4 = *(const float4*)&st[pr * 2048 + n0];
                float4 cv4 = *(const float4*)&ct[pr * 2048 + n0];
                float svv[4] = {sv4.x, sv4.y, sv4.z, sv4.w};
                float cvv[4] = {cv4.x, cv4.y, cv4.z, cv4.w};
                #pragma unroll
                for (int reg = 0; reg < 4; ++reg) {
                    float x = acc[mi][ni][reg] + bi;
                    float p2 = __shfl_xor(x, 1, 64);       // partner column c^1
                    float y = (c & 1) ? fmaf(x, cvv[reg],  p2 * svv[reg])
                                      : fmaf(x, cvv[reg], -p2 * svv[reg]);
                    dst[(((size_t)(bb * Hc + h)) * Nc + n0 + reg) * Dc + d] = y;
                }
            }
        }
    } else if (mode == 2) {
        #pragma unroll
        for (int ni = 0; ni < NI; ++ni) {
            int c = col0 + wc * (TN / WC) + ni * 16 + lrow;
            int h = c >> 6, d = c & 63;
            float bi = bias[c];
            #pragma unroll
            for (int mi = 0; mi < MI; ++mi) {
                int R0 = row0 + wr * (TM / WR) + mi * 16 + quad * 4;
                int bb = R0 >> 11;
                int n0 = R0 & 2047;
                #pragma unroll
                for (int reg = 0; reg < 4; ++reg)
                    Vr[(((size_t)(bb * Hc + h)) * Nc + n0 + reg) * Dc + d] =
                        acc[mi][ni][reg] + bi;
            }
        }
    } else {
        #pragma unroll
        for (int ni = 0; ni < NI; ++ni) {
            int c = col0 + wc * (TN / WC) + ni * 16 + lrow;
            float bi = bias[c];
            #pragma unroll
            for (int mi = 0; mi < MI; ++mi) {
                int R0 = row0 + wr * (TM / WR) + mi * 16 + quad * 4;
                #pragma unroll
                for (int reg = 0; reg < 4; ++reg) {
                    float x = acc[mi][ni][reg] + bi;
                    if (mode == 3)
                        G[(size_t)(R0 + reg) * Ec + c] = x / (1.0f + expf(-x));
                    else
                        Out[(size_t)(R0 + reg) * Ec + c] = x;
                }
            }
        }
    }
}

// ---------------------------------------------------------------------------
// Phase A: per (bh, chunk) local state  L[dk][dv] = sum_s gamma^(64-s) K[s][dk] V[s][dv]
__global__ __launch_bounds__(256) void phaseA_kernel(const float* __restrict__ Kr,
                                                     const float* __restrict__ Vr,
                                                     float* __restrict__ L)
{
    int bh = blockIdx.x;
    int t  = blockIdx.y;
    float gamma = get_gamma(bh & 7);
    float lg = logf(gamma);

    __shared__ float Ks[64][68];
    __shared__ float Vs[64][68];

    int tid = threadIdx.x;
    const float* Kc = Kr + (size_t)(bh * Nc + t * Cc) * Dc;
    const float* Vc = Vr + (size_t)(bh * Nc + t * Cc) * Dc;

    #pragma unroll
    for (int i = 0; i < 4; ++i) {
        int f = tid + i * 256;
        int s = f >> 4;
        int d = (f & 15) << 2;
        float w = expf(lg * (float)(Cc - s));
        float4 kv = *(const float4*)&Kc[s * Dc + d];
        float4 ks = {kv.x * w, kv.y * w, kv.z * w, kv.w * w};
        *(float4*)&Ks[s][d] = ks;
        float4 vv = *(const float4*)&Vc[s * Dc + d];
        *(float4*)&Vs[s][d] = vv;
    }
    __syncthreads();

    int tx = tid & 15, ty = tid >> 4;
    float acc[4][4];
    #pragma unroll
    for (int i = 0; i < 4; ++i)
        #pragma unroll
        for (int j = 0; j < 4; ++j) acc[i][j] = 0.0f;

    for (int s = 0; s < 64; ++s) {
        float4 a = *(const float4*)&Ks[s][ty * 4];
        float4 b = *(const float4*)&Vs[s][tx * 4];
        float av[4] = {a.x, a.y, a.z, a.w};
        float bv[4] = {b.x, b.y, b.z, b.w};
        #pragma unroll
        for (int i = 0; i < 4; ++i)
            #pragma unroll
            for (int j = 0; j < 4; ++j)
                acc[i][j] = fmaf(av[i], bv[j], acc[i][j]);
    }

    float* Lp = L + (size_t)(bh * NT + t) * 4096;
    #pragma unroll
    for (int i = 0; i < 4; ++i) {
        float4 o = {acc[i][0], acc[i][1], acc[i][2], acc[i][3]};
        *(float4*)&Lp[(ty * 4 + i) * 64 + tx * 4] = o;
    }
}

// ---------------------------------------------------------------------------
// Phase B: S_0 = 0 ; S_{t+1} = gamma^64 * S_t + L_t  (S_t written pre-fold)
// grid (16, 4): each block owns one 1024-float quarter of the 64x64 state.
__global__ __launch_bounds__(256) void scan_kernel(const float* __restrict__ L,
                                                   float* __restrict__ Sst)
{
    int bh = blockIdx.x;
    int part = blockIdx.y;
    int tid = threadIdx.x;
    float gamma = get_gamma(bh & 7);
    float g64 = expf(logf(gamma) * 64.0f);

    float4 s = {0.0f, 0.0f, 0.0f, 0.0f};
    size_t base = (size_t)bh * NT * 4096 + part * 1024 + tid * 4;
    const float* Lp = L + base;
    float* Sp = Sst + base;
    for (int t = 0; t < NT; ++t) {
        *(float4*)&Sp[(size_t)t * 4096] = s;
        float4 l = *(const float4*)&Lp[(size_t)t * 4096];
        s.x = s.x * g64 + l.x;
        s.y = s.y * g64 + l.y;
        s.z = s.z * g64 + l.z;
        s.w = s.w * g64 + l.w;
    }
}

// ---------------------------------------------------------------------------
// Phase C: O = tril-decayed(QK^T) @ V + gamma^i * Q @ S, LayerNorm, gate,
// write retG as bf16 hi/lo in (B,N,E) layout.
__global__ __launch_bounds__(256) void phaseC_kernel(
    const float* __restrict__ Qr, const float* __restrict__ Kr, const float* __restrict__ Vr,
    const float* __restrict__ Sst, const float* __restrict__ G,
    unsigned short* __restrict__ retGh, unsigned short* __restrict__ retGl)
{
    int bh = blockIdx.x, t = blockIdx.y;
    int b = bh >> 3, h = bh & 7;
    float gamma = get_gamma(h);
    float lg = logf(gamma);

    __shared__ float QsT[64][68];
    __shared__ float KsT[64][68];
    __shared__ float Ss[64][68];

    int tid = threadIdx.x;
    const float* Qc = Qr + (size_t)(bh * Nc + t * Cc) * Dc;
    const float* Kc = Kr + (size_t)(bh * Nc + t * Cc) * Dc;
    const float* Sp = Sst + (size_t)(bh * NT + t) * 4096;

    #pragma unroll
    for (int i = 0; i < 4; ++i) {
        int f = tid + i * 256;
        int r = f >> 4;
        int d = (f & 15) << 2;
        float wq = expf(lg * (float)r);
        float4 q = *(const float4*)&Qc[r * Dc + d];
        QsT[d + 0][r] = q.x * wq; QsT[d + 1][r] = q.y * wq;
        QsT[d + 2][r] = q.z * wq; QsT[d + 3][r] = q.w * wq;
        float wk = expf(-lg * (float)r);
        float4 kk = *(const float4*)&Kc[r * Dc + d];
        KsT[d + 0][r] = kk.x * wk; KsT[d + 1][r] = kk.y * wk;
        KsT[d + 2][r] = kk.z * wk; KsT[d + 3][r] = kk.w * wk;
        float4 sv = *(const float4*)&Sp[r * 64 + d];
        *(float4*)&Ss[r][d] = sv;
    }
    __syncthreads();

    int tx = tid & 15, ty = tid >> 4;
    float accA[4][4], accO[4][4];
    #pragma unroll
    for (int i = 0; i < 4; ++i)
        #pragma unroll
        for (int j = 0; j < 4; ++j) { accA[i][j] = 0.0f; accO[i][j] = 0.0f; }

    for (int d = 0; d < 64; ++d) {
        float4 a  = *(const float4*)&QsT[d][ty * 4];
        float4 kb = *(const float4*)&KsT[d][tx * 4];
        float4 sb = *(const float4*)&Ss[d][tx * 4];
        float av[4] = {a.x, a.y, a.z, a.w};
        float kv[4] = {kb.x, kb.y, kb.z, kb.w};
        float sv[4] = {sb.x, sb.y, sb.z, sb.w};
        #pragma unroll
        for (int i = 0; i < 4; ++i)
            #pragma unroll
            for (int j = 0; j < 4; ++j) {
                accA[i][j] = fmaf(av[i], kv[j], accA[i][j]);
                accO[i][j] = fmaf(av[i], sv[j], accO[i][j]);
            }
    }
    __syncthreads();

    #pragma unroll
    for (int i = 0; i < 4; ++i) {
        int gi = ty * 4 + i;
        #pragma unroll
        for (int j = 0; j < 4; ++j) {
            int gj = tx * 4 + j;
            KsT[gj][gi] = (gj <= gi) ? accA[i][j] : 0.0f;
        }
    }
    const float* Vc = Vr + (size_t)(bh * Nc + t * Cc) * Dc;
    #pragma unroll
    for (int i = 0; i < 4; ++i) {
        int f = tid + i * 256;
        int r = f >> 4;
        int d = (f & 15) << 2;
        float4 vv = *(const float4*)&Vc[r * Dc + d];
        *(float4*)&QsT[r][d] = vv;
    }
    __syncthreads();

    for (int j = 0; j < 64; ++j) {
        float4 a = *(const float4*)&KsT[j][ty * 4];
        float4 v = *(const float4*)&QsT[j][tx * 4];
        float av[4] = {a.x, a.y, a.z, a.w};
        float vv[4] = {v.x, v.y, v.z, v.w};
        #pragma unroll
        for (int i = 0; i < 4; ++i)
            #pragma unroll
            for (int jj = 0; jj < 4; ++jj)
                accO[i][jj] = fmaf(av[i], vv[jj], accO[i][jj]);
    }

    // LayerNorm over D=64 per row (row spread across 16 tx lanes)
    #pragma unroll
    for (int i = 0; i < 4; ++i) {
        float sum = accO[i][0] + accO[i][1] + accO[i][2] + accO[i][3];
        float sq  = accO[i][0] * accO[i][0] + accO[i][1] * accO[i][1]
                  + accO[i][2] * accO[i][2] + accO[i][3] * accO[i][3];
        #pragma unroll
        for (int m = 1; m < 16; m <<= 1) {
            sum += __shfl_xor(sum, m, 64);
            sq  += __shfl_xor(sq,  m, 64);
        }
        float mean = sum * (1.0f / 64.0f);
        float var  = sq * (1.0f / 64.0f) - mean * mean;
        float rinv = rsqrtf(var + 1e-6f);
        #pragma unroll
        for (int jj = 0; jj < 4; ++jj)
            accO[i][jj] = (accO[i][jj] - mean) * rinv;
    }

    // gate multiply + hi/lo bf16 store to (B, N, E)
    #pragma unroll
    for (int i = 0; i < 4; ++i) {
        int n = t * Cc + ty * 4 + i;
        size_t idx = ((size_t)b * Nc + n) * Ec + h * Dc + tx * 4;
        float4 g = *(const float4*)&G[idx];
        float o0 = accO[i][0] * g.x, o1 = accO[i][1] * g.y;
        float o2 = accO[i][2] * g.z, o3 = accO[i][3] * g.w;
        ushort4 hh, ll;
        hh.x = f2bf(o0); ll.x = f2bf(o0 - bf2f(hh.x));
        hh.y = f2bf(o1); ll.y = f2bf(o1 - bf2f(hh.y));
        hh.z = f2bf(o2); ll.z = f2bf(o2 - bf2f(hh.z));
        hh.w = f2bf(o3); ll.w = f2bf(o3 - bf2f(hh.w));
        *(ushort4*)&retGh[idx] = hh;
        *(ushort4*)&retGl[idx] = ll;
    }
}

// ---------------------------------------------------------------------------
extern "C" void kernel_launch(void* const* d_in, const int* in_sizes, int n_in,
                              void* d_out, int out_size, void* d_ws, size_t ws_size,
                              hipStream_t stream) {
    const float* query = (const float*)d_in[0];
    const float* key   = (const float*)d_in[1];
    const float* value = (const float*)d_in[2];
    const float* Wq = (const float*)d_in[3];
    const float* bq = (const float*)d_in[4];
    const float* Wk = (const float*)d_in[5];
    const float* bk = (const float*)d_in[6];
    const float* Wv = (const float*)d_in[7];
    const float* bv = (const float*)d_in[8];
    const float* Wg = (const float*)d_in[9];
    const float* bg = (const float*)d_in[10];
    const float* Wo = (const float*)d_in[11];
    const float* bo = (const float*)d_in[12];
    float* out = (float*)d_out;

    float* wsf = (float*)d_ws;
    const size_t SZ = (size_t)Bc * Nc * Ec;   // 2,097,152

    float* Qr = wsf;                 // fp32 (B,H,N,D)
    float* Kr = Qr + SZ;
    float* Vr = Kr + SZ;
    float* G  = Vr + SZ;             // fp32 (B,N,E)

    // X hi/lo region [4SZ, 7SZ) floats — dead after fused GEMM, then reused:
    unsigned short* Xq_h = (unsigned short*)(wsf + 4 * SZ);
    unsigned short* Xq_l = Xq_h + SZ;
    unsigned short* Xk_h = Xq_l + SZ;
    unsigned short* Xk_l = Xk_h + SZ;
    unsigned short* Xv_h = Xk_l + SZ;
    unsigned short* Xv_l = Xv_h + SZ;
    float* L   = wsf + 4 * SZ;                       // overlays Xq (after GEMM)
    float* Sst = wsf + 5 * SZ;                       // overlays Xk
    unsigned short* retGh = (unsigned short*)(wsf + 6 * SZ);  // overlays Xv
    unsigned short* retGl = retGh + SZ;

    const size_t WSZ = (size_t)Ec * Ec;      // 262,144
    unsigned short* Wp = (unsigned short*)(wsf + 7 * SZ);
    unsigned short* Wq_h = Wp;            unsigned short* Wq_l = Wp + WSZ;
    unsigned short* Wk_h = Wp + 2 * WSZ;  unsigned short* Wk_l = Wp + 3 * WSZ;
    unsigned short* Wv_h = Wp + 4 * WSZ;  unsigned short* Wv_l = Wp + 5 * WSZ;
    unsigned short* Wg_h = Wp + 6 * WSZ;  unsigned short* Wg_l = Wp + 7 * WSZ;
    unsigned short* Wo_h = Wp + 8 * WSZ;  unsigned short* Wo_l = Wp + 9 * WSZ;

    float* tab = wsf + 7 * SZ + (10 * WSZ) / 2;
    float* sinS  = tab;
    float* cosS  = sinS + Nc * 32;
    float* sinIS = cosS + Nc * 32;
    float* cosIS = sinIS + Nc * 32;

    SplitArgs sa;
    sa.src[0] = query; sa.hi[0] = Xq_h; sa.lo[0] = Xq_l; sa.n[0] = (int)SZ;
    sa.src[1] = key;   sa.hi[1] = Xk_h; sa.lo[1] = Xk_l; sa.n[1] = (int)SZ;
    sa.src[2] = value; sa.hi[2] = Xv_h; sa.lo[2] = Xv_l; sa.n[2] = (int)SZ;
    sa.src[3] = Wq;    sa.hi[3] = Wq_h; sa.lo[3] = Wq_l; sa.n[3] = (int)WSZ;
    sa.src[4] = Wk;    sa.hi[4] = Wk_h; sa.lo[4] = Wk_l; sa.n[4] = (int)WSZ;
    sa.src[5] = Wv;    sa.hi[5] = Wv_h; sa.lo[5] = Wv_l; sa.n[5] = (int)WSZ;
    sa.src[6] = Wg;    sa.hi[6] = Wg_h; sa.lo[6] = Wg_l; sa.n[6] = (int)WSZ;
    sa.src[7] = Wo;    sa.hi[7] = Wo_h; sa.lo[7] = Wo_l; sa.n[7] = (int)WSZ;
    prep_kernel<<<dim3(2048, 9), dim3(256), 0, stream>>>(sa, sinS, cosS, sinIS, cosIS);

    // fused Q/K/V/G projections: 128x256 tiles, 4-phase schedule, 256 blocks
    mgemm_kernel<128, 256, 2, 4><<<dim3(Mc / 128, Ec / 256, 4), dim3(512), 0, stream>>>(
        Xq_h, Xq_l, Xk_h, Xk_l, Xv_h, Xv_l, retGh, retGl,
        Wq_h, Wq_l, Wk_h, Wk_l, Wv_h, Wv_l, Wg_h, Wg_l, Wo_h, Wo_l,
        bq, bk, bv, bg, bo, Qr, Kr, Vr, G, out,
        sinS, cosS, sinIS, cosIS, 0);

    phaseA_kernel<<<dim3(Bc * Hc, NT), dim3(256), 0, stream>>>(Kr, Vr, L);
    scan_kernel<<<dim3(Bc * Hc, 4), dim3(256), 0, stream>>>(L, Sst);
    phaseC_kernel<<<dim3(Bc * Hc, NT), dim3(256), 0, stream>>>(Qr, Kr, Vr, Sst, G, retGh, retGl);

    // final: out = retG @ Wo^T + bo, 64x128 tiles, 4-phase schedule, 256 blocks
    mgemm_kernel<64, 128, 2, 2><<<dim3(Mc / 64, Ec / 128, 1), dim3(256), 0, stream>>>(
        Xq_h, Xq_l, Xk_h, Xk_l, Xv_h, Xv_l, retGh, retGl,
        Wq_h, Wq_l, Wk_h, Wk_l, Wv_h, Wv_l, Wg_h, Wg_l, Wo_h, Wo_l,
        bq, bk, bv, bg, bo, Qr, Kr, Vr, G, out,
        sinS, cosS, sinIS, cosIS, 4);
}